// Round 6
// baseline (1104.342 us; speedup 1.0000x reference)
//
#include <hip/hip_runtime.h>
#include <cstdint>
#include <cstddef>

#define B_DIM 128
#define T_LEN 2048
#define C_DIM 128
#define NSTEP (T_LEN - 1)   // 2047 transition steps
#define NS4   512           // bp4-path dword-rows

// Skew for 32-float chunks: F(x) = x + 8*(x>>5) (chunk c at 40c). Verified
// conflict-free (R1/R5: SQ_LDS_BANK_CONFLICT == 0).
#define FSKEW(x) ((x) + 8 * ((x) >> 5))
// Skew for 16-float chunks: F16(x) = x + 4*(x>>4) (chunk c at 20c). Per
// ds_read_b128 instruction, the 8 chunks' bank quartets are
// (20*d3 + 4e) % 32 = {0,20,8,28,16,4,24,12}+4e -> 8 DISJOINT quartets,
// 8 lanes same-addr broadcast each => conflict-free.
#define FSKEW16(x) ((x) + 4 * ((x) >> 4))

// Barrier WITHOUT vmcnt drain: cross-wave LDS visibility only needs
// lgkmcnt(0). Global loads/stores stay in flight across the barrier.
#define LDS_BARRIER() asm volatile("s_waitcnt lgkmcnt(0)\n\ts_barrier" ::: "memory")

#define TR16_LIST(X) \
    X(0)  X(1)  X(2)  X(3)  X(4)  X(5)  X(6)  X(7)  \
    X(8)  X(9)  X(10) X(11) X(12) X(13) X(14) X(15)

#define TR_LIST(X) \
    X(0)  X(1)  X(2)  X(3)  X(4)  X(5)  X(6)  X(7)  \
    X(8)  X(9)  X(10) X(11) X(12) X(13) X(14) X(15) \
    X(16) X(17) X(18) X(19) X(20) X(21) X(22) X(23) \
    X(24) X(25) X(26) X(27) X(28) X(29) X(30) X(31)

template <int CTRL>
__device__ __forceinline__ float dppf(float x)
{
    return __int_as_float(__builtin_amdgcn_update_dpp(
        0, __float_as_int(x), CTRL, 0xF, 0xF, true));
}

// exact 16-way max, fuses to v_max3 (static indexing only)
__device__ __forceinline__ float max16(const float s[16])
{
    const float u0 = fmaxf(fmaxf(s[0], s[1]), s[2]);
    const float u1 = fmaxf(fmaxf(s[3], s[4]), s[5]);
    const float u2 = fmaxf(fmaxf(s[6], s[7]), s[8]);
    const float u3 = fmaxf(fmaxf(s[9], s[10]), s[11]);
    const float u4 = fmaxf(s[12], s[13]);
    const float u5 = fmaxf(s[14], s[15]);
    return fmaxf(fmaxf(fmaxf(u0, u1), fmaxf(u2, u3)), fmaxf(u4, u5));
}

// exact 32-way max (fallback path)
__device__ __forceinline__ float max32(const float s[32])
{
    float u[11];
#pragma unroll
    for (int p = 0; p < 10; ++p)
        u[p] = fmaxf(fmaxf(s[3 * p], s[3 * p + 1]), s[3 * p + 2]);
    u[10] = fmaxf(s[30], s[31]);
    const float w0 = fmaxf(fmaxf(u[0], u[1]), u[2]);
    const float w1 = fmaxf(fmaxf(u[3], u[4]), u[5]);
    const float w2 = fmaxf(fmaxf(u[6], u[7]), u[8]);
    const float w3 = fmaxf(u[9], u[10]);
    return fmaxf(fmaxf(w0, w1), fmaxf(w2, w3));
}

// ===========================================================================
// Forward, value-only, 16 WAVES (1024 thr) = 4 waves/SIMD, one batch/block.
// R5's accounting: 694 cyc/step with 220 cyc VALU issue (VALUBusy 33%) =>
// ~470 cyc of chain stall (barrier -> ds_read 120 -> tree -> write ->
// barrier) shared by only 2 waves/SIMD. 4 waves/SIMD staggers 4 chain
// instances per SIMD; per-SIMD VALU issue stays ~256 cyc (4 x 32 instr).
// Wave w owns columns [8w, 8w+8); lane: m = l>>3 -> j = 8w+m, d3 = l&7 ->
// i in [16*d3, 16*d3+16). Reduction over d3: DPP xor1 (0xB1), xor2 (0x4E),
// xor7 (row_half_mirror 0x141) -- {1,2,7} generates d3-group 0..7
// (numerically verified in R3). FSKEW16 proven conflict-free per
// instruction (header comment). Fully branchless (R5-verified pattern):
// clamped prefetch, all-8-lane dup LDS/global writes.
// ===========================================================================
__global__ __launch_bounds__(1024)
void viterbi_fwd_a16(
    const float* __restrict__ pot,
    const float* __restrict__ trans,
    float* __restrict__ vstarG,        // [B][2047][C]: row t-1 = vstar_t
    int* __restrict__ lastTag)
{
    const int b   = blockIdx.x;
    const int tid = threadIdx.x;
    const int w   = tid >> 6;          // 0..15
    const int l   = tid & 63;
    const int d3  = l & 7;             // i-chunk: [16*d3, 16*d3+16)
    const int m   = l >> 3;            // 0..7
    const int j   = 8 * w + m;
    const int fj  = FSKEW16(j);
    const int ib  = 16 * d3;

    __shared__ __align__(16) float alphabuf[2][160];

#define DECL_TR(K) const float tr_##K = trans[(ib + (K)) * C_DIM + j];
    TR16_LIST(DECL_TR)
#undef DECL_TR

    const float* potb = pot + (size_t)b * T_LEN * C_DIM;
    float* vG = vstarG + (size_t)b * NSTEP * C_DIM;

    // alpha0 = pot[:,0] into buf[1] (step t=1 reads buf[t&1]=buf[1])
    if (tid < C_DIM) alphabuf[1][FSKEW16(tid)] = potb[tid];

    // pot prefetch queue, depth 4, ALL lanes (branchless)
    float pq0 = potb[1 * C_DIM + j];
    float pq1 = potb[2 * C_DIM + j];
    float pq2 = potb[3 * C_DIM + j];
    float pq3 = potb[4 * C_DIM + j];
    __syncthreads();   // init barrier: full drain once, fine

#define ADD_TR(K) s_[K] = a_[K] + tr_##K;

#define STEP_A(T_, PQ_)                                                       \
    {                                                                         \
        const float* ac_ = &alphabuf[(T_) & 1][20 * d3];                      \
        float a_[16];                                                         \
        _Pragma("unroll")                                                     \
        for (int e_ = 0; e_ < 4; ++e_)                                        \
            *(float4*)&a_[4 * e_] = *(const float4*)&ac_[4 * e_];             \
        float s_[16];                                                         \
        TR16_LIST(ADD_TR)                                                     \
        float v_ = max16(s_);                                                 \
        v_ = fmaxf(v_, dppf<0xB1>(v_));    /* xor1 */                         \
        v_ = fmaxf(v_, dppf<0x4E>(v_));    /* xor2 */                         \
        v_ = fmaxf(v_, dppf<0x141>(v_));   /* xor7: d3 {0-3}<->{4-7} */       \
        const float av_ = v_ + (PQ_);                                         \
        alphabuf[((T_) + 1) & 1][fj] = av_;                                   \
        vG[(size_t)((T_) - 1) * C_DIM + j] = v_;                              \
        const int tn_ = ((T_) + 4 < T_LEN) ? ((T_) + 4) : (T_LEN - 1);        \
        PQ_ = potb[tn_ * C_DIM + j];   /* clamped rows never consumed */      \
        LDS_BARRIER();                                                        \
    }

    // main loop: t = 1 .. 2044 (groups of 4 for the pot-queue rotation)
    for (int t = 1; t < 2045; t += 4) {
        STEP_A(t + 0, pq0)
        STEP_A(t + 1, pq1)
        STEP_A(t + 2, pq2)
        STEP_A(t + 3, pq3)
    }
    // tail: t = 2045, 2046, 2047
    STEP_A(2045, pq0)
    STEP_A(2046, pq1)
    STEP_A(2047, pq2)
#undef STEP_A
#undef ADD_TR

    // last_tag = first-index argmax of final alpha (in buf[0]), wave 0
    if (tid < 64) {
        const float* af = alphabuf[0];
        const float v0 = af[FSKEW16(tid)];
        const float v1 = af[FSKEW16(tid + 64)];
        float v = v0; int x = tid;
        if (v1 > v0) { v = v1; x = tid + 64; }
#pragma unroll
        for (int mk = 1; mk < 64; mk <<= 1) {
            const float pv = __shfl_xor(v, mk);
            const int   px = __shfl_xor(x, mk);
            if (pv > v || (pv == v && px < x)) { v = pv; x = px; }
        }
        if (tid == 0) lastTag[b] = x;
    }
}

// ===========================================================================
// Reduction-free backtrack, BRANCHLESS loads (R5-verified, ~505 us).
// smax = vstar_t[cur] via register readlane; argmax = equality-ballot +
// ffs. Unconditional clamped prefetch, all-lane uniform out stores.
// ===========================================================================
__global__ __launch_bounds__(64, 1) void viterbi_bwd_v(
    const float* __restrict__ pot,
    const float* __restrict__ vstarG,
    const float* __restrict__ trans,
    const int* __restrict__ lastTag,
    float* __restrict__ out)
{
    const int b = blockIdx.x;
    const int l = threadIdx.x;
    float* outb = out + (size_t)b * T_LEN;
    const float* potb = pot + (size_t)b * T_LEN * C_DIM;
    const float* vbse = vstarG + (size_t)b * NSTEP * C_DIM;

    __shared__ float Tl[C_DIM][C_DIM];   // 64 KiB, swizzled
    for (int k = l; k < C_DIM * C_DIM; k += 64) {
        const int i = k >> 7;
        const int jj = k & 127;
        Tl[i][jj ^ (i & 31)] = trans[k];
    }

    // queues over row index r, walking 2046 -> 0 (depth 6):
    // p*: pot row r ; v*: vstarG row r (= vstar_{r+1})
    float pa0, pb0, pa1, pb1, pa2, pb2, pa3, pb3, pa4, pb4, pa5, pb5;
    float va0, vb0, va1, vb1, va2, vb2, va3, vb3, va4, vb4, va5, vb5;
    auto ld = [&](int r, float& pa, float& pb, float& va, float& vb) {
        const int rr = (r > 0) ? r : 0;        // clamped, branchless
        pa = potb[(size_t)rr * C_DIM + l];
        pb = potb[(size_t)rr * C_DIM + l + 64];
        va = vbse[(size_t)rr * C_DIM + l];
        vb = vbse[(size_t)rr * C_DIM + l + 64];
    };
    ld(2046, pa0, pb0, va0, vb0);
    ld(2045, pa1, pb1, va1, vb1);
    ld(2044, pa2, pb2, va2, vb2);
    ld(2043, pa3, pb3, va3, vb3);
    ld(2042, pa4, pb4, va4, vb4);
    ld(2041, pa5, pb5, va5, vb5);

    int cur = lastTag[b];
    outb[T_LEN - 1] = (float)cur;        // uniform all-lane store
    __syncthreads();   // Tl visibility

    for (int r = NSTEP - 1; r >= 1; --r) {     // r = t-1 ; r-1 >= 0 here
        // smax = vstar_{r+1}[cur]  (row r, in registers)
        const int cl = cur & 63;
        const float rl0 = __int_as_float(
            __builtin_amdgcn_readlane(__float_as_int(va0), cl));
        const float rl1 = __int_as_float(
            __builtin_amdgcn_readlane(__float_as_int(vb0), cl));
        const float smax = (cur & 64) ? rl1 : rl0;
        // alpha_r (exact replay): pot_r + vstar_r (row r-1)
        const float a0 = pa0 + va1;
        const float a1 = pb0 + vb1;
        // T[:,cur] gather (conflict-free swizzle)
        const int sw = cur ^ (l & 31);
        const float c0 = Tl[l][sw];
        const float c1 = Tl[l + 64][sw];
        const float s0 = a0 + c0;
        const float s1 = a1 + c1;
        // exact first-index argmax: lowest i with s_i == smax
        const unsigned long long m0 = __ballot(s0 == smax);
        const unsigned long long m1 = __ballot(s1 == smax);
        cur = m0 ? (__ffsll(m0) - 1) : (64 + __ffsll(m1) - 1);
        outb[r] = (float)cur;            // uniform all-lane store
        // rotate queues, prefetch row r-6 (clamped)
        pa0 = pa1; pb0 = pb1; va0 = va1; vb0 = vb1;
        pa1 = pa2; pb1 = pb2; va1 = va2; vb1 = vb2;
        pa2 = pa3; pb2 = pb3; va2 = va3; vb2 = vb3;
        pa3 = pa4; pb3 = pb4; va3 = va4; vb3 = vb4;
        pa4 = pa5; pb4 = pb5; va4 = va5; vb4 = vb5;
        ld(r - 6, pa5, pb5, va5, vb5);
    }
    // peeled r = 0 (t = 1): vstar_{-1} = 0 -> alpha_0 = pot_0
    {
        const int cl = cur & 63;
        const float rl0 = __int_as_float(
            __builtin_amdgcn_readlane(__float_as_int(va0), cl));
        const float rl1 = __int_as_float(
            __builtin_amdgcn_readlane(__float_as_int(vb0), cl));
        const float smax = (cur & 64) ? rl1 : rl0;
        const float a0 = pa0;
        const float a1 = pb0;
        const int sw = cur ^ (l & 31);
        const float s0 = a0 + Tl[l][sw];
        const float s1 = a1 + Tl[l + 64][sw];
        const unsigned long long m0 = __ballot(s0 == smax);
        const unsigned long long m1 = __ballot(s1 == smax);
        cur = m0 ? (__ffsll(m0) - 1) : (64 + __ffsll(m1) - 1);
        outb[0] = (float)cur;
    }
}

// ===========================================================================
// FULL FALLBACK (bp4, 32 MiB workspace): verbatim verified kernels.
// ===========================================================================
__global__ __launch_bounds__(512)
__attribute__((amdgpu_waves_per_eu(2, 2)))
void viterbi_fwd(
    const float* __restrict__ pot,
    const float* __restrict__ trans,
    unsigned* __restrict__ bp4,
    int* __restrict__ lastTag)
{
    const int b   = blockIdx.x;
    const int tid = threadIdx.x;
    const int w   = tid >> 6;
    const int l   = tid & 63;
    const int d   = l & 3;
    const int j   = 16 * w + (l >> 2);
    const int fj  = FSKEW(j);
    const int ib  = 32 * d;

    __shared__ __align__(16) float alphabuf[2][160];

#define DECL_TR(K) float tr_##K = trans[(ib + (K)) * C_DIM + j];
    TR_LIST(DECL_TR)
#undef DECL_TR

    const float* potb = pot + (size_t)b * T_LEN * C_DIM;

    if (tid < C_DIM) alphabuf[1][FSKEW(tid)] = potb[tid];

    float pq0 = 0.f, pq1 = 0.f, pq2 = 0.f, pq3 = 0.f;
    if (d == 0) {
        pq0 = potb[1 * C_DIM + j];
        pq1 = potb[2 * C_DIM + j];
        pq2 = potb[3 * C_DIM + j];
        pq3 = potb[4 * C_DIM + j];
    }
    unsigned pack = 0;
    __syncthreads();

#define ADD_TR(K) s_[K] = a_[K] + tr_##K;

#define STEP(T_, C_, PQ_)                                                     \
    {                                                                         \
        const float* ac_ = &alphabuf[(T_) & 1][40 * d];                       \
        float a_[32];                                                         \
        _Pragma("unroll")                                                     \
        for (int e_ = 0; e_ < 8; ++e_)                                        \
            *(float4*)&a_[4 * e_] = *(const float4*)&ac_[4 * e_];             \
        float s_[32];                                                         \
        TR_LIST(ADD_TR)                                                       \
        float v16_[16]; int x16_[16];                                         \
        _Pragma("unroll")                                                     \
        for (int p_ = 0; p_ < 16; ++p_) {                                     \
            const bool g_ = s_[2 * p_ + 1] > s_[2 * p_];                      \
            v16_[p_] = g_ ? s_[2 * p_ + 1] : s_[2 * p_];                      \
            x16_[p_] = g_ ? 2 * p_ + 1 : 2 * p_;                              \
        }                                                                     \
        float v8_[8]; int x8_[8];                                             \
        _Pragma("unroll")                                                     \
        for (int p_ = 0; p_ < 8; ++p_) {                                      \
            const bool g_ = v16_[2 * p_ + 1] > v16_[2 * p_];                  \
            v8_[p_] = g_ ? v16_[2 * p_ + 1] : v16_[2 * p_];                   \
            x8_[p_] = g_ ? x16_[2 * p_ + 1] : x16_[2 * p_];                   \
        }                                                                     \
        float v4_[4]; int x4_[4];                                             \
        _Pragma("unroll")                                                     \
        for (int p_ = 0; p_ < 4; ++p_) {                                      \
            const bool g_ = v8_[2 * p_ + 1] > v8_[2 * p_];                    \
            v4_[p_] = g_ ? v8_[2 * p_ + 1] : v8_[2 * p_];                     \
            x4_[p_] = g_ ? x8_[2 * p_ + 1] : x8_[2 * p_];                     \
        }                                                                     \
        float v2_[2]; int x2_[2];                                             \
        _Pragma("unroll")                                                     \
        for (int p_ = 0; p_ < 2; ++p_) {                                      \
            const bool g_ = v4_[2 * p_ + 1] > v4_[2 * p_];                    \
            v2_[p_] = g_ ? v4_[2 * p_ + 1] : v4_[2 * p_];                     \
            x2_[p_] = g_ ? x4_[2 * p_ + 1] : x4_[2 * p_];                     \
        }                                                                     \
        const bool gf_ = v2_[1] > v2_[0];                                     \
        float v_ = gf_ ? v2_[1] : v2_[0];                                     \
        int   x_ = ib + (gf_ ? x2_[1] : x2_[0]);                              \
        {                                                                     \
            const float pv_ = __int_as_float(__builtin_amdgcn_update_dpp(     \
                0, __float_as_int(v_), 0xB1, 0xF, 0xF, true));                \
            const int   px_ = __builtin_amdgcn_update_dpp(                    \
                0, x_, 0xB1, 0xF, 0xF, true);                                 \
            const bool  pl_ = d & 1;                                          \
            const bool  tk_ = (pv_ > v_) || (pl_ && (pv_ == v_));             \
            if (tk_) { v_ = pv_; x_ = px_; }                                  \
        }                                                                     \
        {                                                                     \
            const float pv_ = __int_as_float(__builtin_amdgcn_update_dpp(     \
                0, __float_as_int(v_), 0x4E, 0xF, 0xF, true));                \
            const int   px_ = __builtin_amdgcn_update_dpp(                    \
                0, x_, 0x4E, 0xF, 0xF, true);                                 \
            const bool  pl_ = (d >> 1) & 1;                                   \
            const bool  tk_ = (pv_ > v_) || (pl_ && (pv_ == v_));             \
            if (tk_) { v_ = pv_; x_ = px_; }                                  \
        }                                                                     \
        if (d == 0) {                                                         \
            alphabuf[((T_) + 1) & 1][fj] = v_ + (PQ_);                        \
            pack |= (unsigned)x_ << (8 * (C_));                               \
            if ((C_) == 3) {                                                  \
                bp4[((size_t)(((T_) - 1) >> 2) * B_DIM + b) * C_DIM + j] =    \
                    pack;                                                     \
                pack = 0;                                                     \
            }                                                                 \
            if ((T_) + 4 < T_LEN) PQ_ = potb[((T_) + 4) * C_DIM + j];         \
        }                                                                     \
        LDS_BARRIER();                                                        \
    }

    for (int t = 1; t < 2045; t += 4) {
        STEP(t + 0, 0, pq0)
        STEP(t + 1, 1, pq1)
        STEP(t + 2, 2, pq2)
        STEP(t + 3, 3, pq3)
    }
    STEP(2045, 0, pq0)
    STEP(2046, 1, pq1)
    STEP(2047, 2, pq2)
    if (d == 0)
        bp4[((size_t)511 * B_DIM + b) * C_DIM + j] = pack;
#undef STEP
#undef ADD_TR

    if (tid < 64) {
        const float* af = alphabuf[0];
        const float v0 = af[FSKEW(tid)];
        const float v1 = af[FSKEW(tid + 64)];
        float v = v0; int x = tid;
        if (v1 > v0) { v = v1; x = tid + 64; }
#pragma unroll
        for (int mk = 1; mk < 64; mk <<= 1) {
            const float pv = __shfl_xor(v, mk);
            const int   px = __shfl_xor(x, mk);
            if (pv > v || (pv == v && px < x)) { v = pv; x = px; }
        }
        if (tid == 0) lastTag[b] = x;
    }
}

__global__ __launch_bounds__(64, 1) void viterbi_bwd(
    const unsigned* __restrict__ bp4,
    const int* __restrict__ lastTag,
    float* __restrict__ out)
{
    const int b = blockIdx.x;
    const int l = threadIdx.x;
    float* outb = out + (size_t)b * T_LEN;

    unsigned qa0 = 0, qb0 = 0, qa1 = 0, qb1 = 0,
             qa2 = 0, qb2 = 0, qa3 = 0, qb3 = 0;

    auto ld = [&](int s4, unsigned& A, unsigned& B) {
        if (s4 >= 0) {
            const unsigned* r = bp4 + ((size_t)s4 * B_DIM + b) * C_DIM;
            A = r[l];
            B = r[l + 64];
        }
    };
    ld(511, qa0, qb0);
    ld(510, qa1, qb1);
    ld(509, qa2, qb2);
    ld(508, qa3, qb3);

    int cur = lastTag[b];

    auto ext = [&](unsigned rA, unsigned rB, int c, int byte) -> int {
        const int addr = (c & 63) << 2;
        const int vA = __builtin_amdgcn_ds_bpermute(addr, (int)rA);
        const int vB = __builtin_amdgcn_ds_bpermute(addr, (int)rB);
        const int v = (c & 64) ? vB : vA;
        return (v >> (byte * 8)) & 0xFF;
    };

    {
        const unsigned rA = qa0, rB = qb0;
        const float t3 = (float)cur;
        cur = ext(rA, rB, cur, 2); const float t2 = (float)cur;
        cur = ext(rA, rB, cur, 1); const float t1 = (float)cur;
        cur = ext(rA, rB, cur, 0); const float t0 = (float)cur;
        if (l == 0) *(float4*)(outb + 4 * 511) = make_float4(t0, t1, t2, t3);
        qa0 = qa1; qb0 = qb1; qa1 = qa2; qb1 = qb2; qa2 = qa3; qb2 = qb3;
        ld(507, qa3, qb3);
    }

    for (int s4 = 510; s4 >= 0; --s4) {
        const unsigned rA = qa0, rB = qb0;
        cur = ext(rA, rB, cur, 3); const float t3 = (float)cur;
        cur = ext(rA, rB, cur, 2); const float t2 = (float)cur;
        cur = ext(rA, rB, cur, 1); const float t1 = (float)cur;
        cur = ext(rA, rB, cur, 0); const float t0 = (float)cur;
        if (l == 0) *(float4*)(outb + 4 * s4) = make_float4(t0, t1, t2, t3);
        qa0 = qa1; qb0 = qb1; qa1 = qa2; qb1 = qb2; qa2 = qa3; qb2 = qb3;
        ld(s4 - 4, qa3, qb3);
    }
}

extern "C" void kernel_launch(void* const* d_in, const int* in_sizes, int n_in,
                              void* d_out, int out_size, void* d_ws, size_t ws_size,
                              hipStream_t stream)
{
    const float* pot   = (const float*)d_in[0];   // [128, 2048, 128] f32
    const float* trans = (const float*)d_in[1];   // [128, 128] f32
    float* out = (float*)d_out;                   // [128, 2048] f32 (tags)

    const size_t vstarBytes = (size_t)B_DIM * NSTEP * C_DIM * sizeof(float); // 134,152,192

    if (ws_size >= vstarBytes + 512) {
        // V*-store forward (16-wave) + reduction-free backtrack
        float* vstarG = (float*)d_ws;
        int* lastTag  = (int*)((char*)d_ws + vstarBytes);
        viterbi_fwd_a16<<<B_DIM, 1024, 0, stream>>>(pot, trans, vstarG, lastTag);
        viterbi_bwd_v<<<B_DIM, 64, 0, stream>>>(pot, vstarG, trans, lastTag, out);
    } else {
        // FALLBACK: bp4 path (32 MiB workspace)
        unsigned* bp4 = (unsigned*)d_ws;
        int* lastTag  = (int*)((char*)d_ws + (size_t)NS4 * B_DIM * C_DIM * 4);
        viterbi_fwd<<<B_DIM, 512, 0, stream>>>(pot, trans, bp4, lastTag);
        viterbi_bwd<<<B_DIM, 64, 0, stream>>>(bp4, lastTag, out);
    }
}

// Round 7
// 966.360 us; speedup vs baseline: 1.1428x; 1.1428x over previous
//
#include <hip/hip_runtime.h>
#include <cstdint>
#include <cstddef>

#define B_DIM 128
#define T_LEN 2048
#define C_DIM 128
#define NSTEP (T_LEN - 1)   // 2047 transition steps
#define NS4   512           // bp4-path dword-rows

// Skew for 32-float chunks: F(x) = x + 8*(x>>5) (chunk c at 40c). Verified
// conflict-free (R1/R5: SQ_LDS_BANK_CONFLICT == 0).
#define FSKEW(x) ((x) + 8 * ((x) >> 5))

// Barrier WITHOUT vmcnt drain: cross-wave LDS visibility only needs
// lgkmcnt(0). Global loads/stores stay in flight across the barrier.
#define LDS_BARRIER() asm volatile("s_waitcnt lgkmcnt(0)\n\ts_barrier" ::: "memory")

#define TR_LIST(X) \
    X(0)  X(1)  X(2)  X(3)  X(4)  X(5)  X(6)  X(7)  \
    X(8)  X(9)  X(10) X(11) X(12) X(13) X(14) X(15) \
    X(16) X(17) X(18) X(19) X(20) X(21) X(22) X(23) \
    X(24) X(25) X(26) X(27) X(28) X(29) X(30) X(31)

template <int CTRL>
__device__ __forceinline__ float dppf(float x)
{
    return __int_as_float(__builtin_amdgcn_update_dpp(
        0, __float_as_int(x), CTRL, 0xF, 0xF, true));
}

// exact 32-way max, fuses to v_max3 chains (static indexing only)
__device__ __forceinline__ float max32(const float s[32])
{
    float u[11];
#pragma unroll
    for (int p = 0; p < 10; ++p)
        u[p] = fmaxf(fmaxf(s[3 * p], s[3 * p + 1]), s[3 * p + 2]);
    u[10] = fmaxf(s[30], s[31]);
    const float w0 = fmaxf(fmaxf(u[0], u[1]), u[2]);
    const float w1 = fmaxf(fmaxf(u[3], u[4]), u[5]);
    const float w2 = fmaxf(fmaxf(u[6], u[7]), u[8]);
    const float w3 = fmaxf(u[9], u[10]);
    return fmaxf(fmaxf(w0, w1), fmaxf(w2, w3));
}

// ===========================================================================
// Forward, value-only, FULLY BRANCHLESS (R5-verified: 592 us, 0 conflicts).
// One block per batch, 512 threads = 8 waves (2/SIMD). Wave w owns j in
// [16w,16w+16); lane l: j = 16w + (l>>2), d = l&3, i in [32d,32d+32).
// All-lane dup writes (post-DPP all 4 quad lanes hold v_), clamped
// unconditional prefetch => precise vmcnt counting, loads stay in flight.
// ===========================================================================
__global__ __launch_bounds__(512)
__attribute__((amdgpu_waves_per_eu(2, 2)))
void viterbi_fwd_a(
    const float* __restrict__ pot,
    const float* __restrict__ trans,
    float* __restrict__ vstarG,        // [B][2047][C]: row t-1 = vstar_t
    int* __restrict__ lastTag)
{
    const int b   = blockIdx.x;
    const int tid = threadIdx.x;
    const int w   = tid >> 6;
    const int l   = tid & 63;
    const int d   = l & 3;             // i-chunk: [32d, 32d+32)
    const int j   = 16 * w + (l >> 2);
    const int fj  = FSKEW(j);
    const int ib  = 32 * d;

    __shared__ __align__(16) float alphabuf[2][160];

#define DECL_TR(K) const float tr_##K = trans[(ib + (K)) * C_DIM + j];
    TR_LIST(DECL_TR)
#undef DECL_TR

    const float* potb = pot + (size_t)b * T_LEN * C_DIM;
    float* vG = vstarG + (size_t)b * NSTEP * C_DIM;

    // alpha0 = pot[:,0] into buf[1] (step t=1 reads buf[t&1]=buf[1])
    if (tid < C_DIM) alphabuf[1][FSKEW(tid)] = potb[tid];

    // pot prefetch queue, depth 4, ALL lanes (branchless)
    float pq0 = potb[1 * C_DIM + j];
    float pq1 = potb[2 * C_DIM + j];
    float pq2 = potb[3 * C_DIM + j];
    float pq3 = potb[4 * C_DIM + j];
    __syncthreads();   // init barrier: full drain once, fine

#define ADD_TR(K) s_[K] = a_[K] + tr_##K;

#define STEP_A(T_, PQ_)                                                       \
    {                                                                         \
        const float* ac_ = &alphabuf[(T_) & 1][40 * d];                       \
        float a_[32];                                                         \
        _Pragma("unroll")                                                     \
        for (int e_ = 0; e_ < 8; ++e_)                                        \
            *(float4*)&a_[4 * e_] = *(const float4*)&ac_[4 * e_];             \
        float s_[32];                                                         \
        TR_LIST(ADD_TR)                                                       \
        float v_ = max32(s_);                                                 \
        v_ = fmaxf(v_, dppf<0xB1>(v_));                                       \
        v_ = fmaxf(v_, dppf<0x4E>(v_));                                       \
        const float av_ = v_ + (PQ_);                                         \
        alphabuf[((T_) + 1) & 1][fj] = av_;                                   \
        vG[(size_t)((T_) - 1) * C_DIM + j] = v_;                              \
        const int tn_ = ((T_) + 4 < T_LEN) ? ((T_) + 4) : (T_LEN - 1);        \
        PQ_ = potb[tn_ * C_DIM + j];   /* clamped rows never consumed */      \
        LDS_BARRIER();                                                        \
    }

    // main loop: t = 1 .. 2044 (groups of 4 for the pot-queue rotation)
    for (int t = 1; t < 2045; t += 4) {
        STEP_A(t + 0, pq0)
        STEP_A(t + 1, pq1)
        STEP_A(t + 2, pq2)
        STEP_A(t + 3, pq3)
    }
    // tail: t = 2045, 2046, 2047
    STEP_A(2045, pq0)
    STEP_A(2046, pq1)
    STEP_A(2047, pq2)
#undef STEP_A
#undef ADD_TR

    // last_tag = first-index argmax of final alpha (in buf[0]), wave 0
    if (tid < 64) {
        const float* af = alphabuf[0];
        const float v0 = af[FSKEW(tid)];
        const float v1 = af[FSKEW(tid + 64)];
        float v = v0; int x = tid;
        if (v1 > v0) { v = v1; x = tid + 64; }
#pragma unroll
        for (int mk = 1; mk < 64; mk <<= 1) {
            const float pv = __shfl_xor(v, mk);
            const int   px = __shfl_xor(x, mk);
            if (pv > v || (pv == v && px < x)) { v = pv; x = px; }
        }
        if (tid == 0) lastTag[b] = x;
    }
}

// ===========================================================================
// Reduction-free backtrack, STATIC 6-SLOT circular queue (no rotation
// movs). R5's bwd rotated the queue with v_movs: `pa4 = pa5` consumes the
// load issued only ONE iteration (~590 cyc) earlier, but HBM latency is
// ~900 cyc -> every iteration stalled ~300 cyc on that mov's waitcnt,
// collapsing the 6-deep queue to depth-1 (measured 592 cyc/step for a
// ~150 cyc chain). Fix: unroll rows in groups of 6 (2046 = 6*341 exactly)
// with NAMED slot registers; slot u is reloaded right after body u
// consumes it and is next read 5-6 bodies (~1000+ cyc) later.
// Body: smax = vstar_{r+1}[cur] via readlane; alpha replay pa+va;
// T[:,cur] swizzled LDS gather; equality-ballot + ffs (exact first-index).
// ===========================================================================
__global__ __launch_bounds__(64, 1) void viterbi_bwd_v(
    const float* __restrict__ pot,
    const float* __restrict__ vstarG,
    const float* __restrict__ trans,
    const int* __restrict__ lastTag,
    float* __restrict__ out)
{
    const int b = blockIdx.x;
    const int l = threadIdx.x;
    float* outb = out + (size_t)b * T_LEN;
    const float* potb = pot + (size_t)b * T_LEN * C_DIM;
    const float* vbse = vstarG + (size_t)b * NSTEP * C_DIM;

    __shared__ float Tl[C_DIM][C_DIM];   // 64 KiB, swizzled
    for (int k = l; k < C_DIM * C_DIM; k += 64) {
        const int i = k >> 7;
        const int jj = k & 127;
        Tl[i][jj ^ (i & 31)] = trans[k];
    }

    // 6 static slots; slot u holds rows descending by 6.
    float pa0, pb0, va0, vb0, pa1, pb1, va1, vb1, pa2, pb2, va2, vb2,
          pa3, pb3, va3, vb3, pa4, pb4, va4, vb4, pa5, pb5, va5, vb5;
    auto ldrow = [&](int r, float& pa, float& pb, float& va, float& vb) {
        const int rr = (r > 0) ? r : 0;        // clamped, branchless
        pa = potb[(size_t)rr * C_DIM + l];
        pb = potb[(size_t)rr * C_DIM + l + 64];
        va = vbse[(size_t)rr * C_DIM + l];
        vb = vbse[(size_t)rr * C_DIM + l + 64];
    };
    ldrow(2046, pa0, pb0, va0, vb0);
    ldrow(2045, pa1, pb1, va1, vb1);
    ldrow(2044, pa2, pb2, va2, vb2);
    ldrow(2043, pa3, pb3, va3, vb3);
    ldrow(2042, pa4, pb4, va4, vb4);
    ldrow(2041, pa5, pb5, va5, vb5);

    int cur = lastTag[b];
    outb[T_LEN - 1] = (float)cur;        // uniform all-lane store
    __syncthreads();   // Tl visibility

    // BODY(slot u regs, slot u+1 va/vb (= row RROW-1), RROW):
    // consumes slot u (row RROW), emits tag for row RROW, reloads slot u
    // with row RROW-6 (consumed 6 bodies later; as replay 5 bodies later).
#define BODY(PAu, PBu, VAu, VBu, VAn, VBn, RROW)                              \
    {                                                                         \
        const int cl = cur & 63;                                              \
        const float rl0 = __int_as_float(                                     \
            __builtin_amdgcn_readlane(__float_as_int(VAu), cl));              \
        const float rl1 = __int_as_float(                                     \
            __builtin_amdgcn_readlane(__float_as_int(VBu), cl));              \
        const float smax = (cur & 64) ? rl1 : rl0;                            \
        const int sw = cur ^ (l & 31);                                        \
        const float c0 = Tl[l][sw];                                           \
        const float c1 = Tl[l + 64][sw];                                      \
        const float s0 = (PAu + VAn) + c0;                                    \
        const float s1 = (PBu + VBn) + c1;                                    \
        const unsigned long long m0 = __ballot(s0 == smax);                   \
        const unsigned long long m1 = __ballot(s1 == smax);                   \
        cur = m0 ? (__ffsll(m0) - 1) : (64 + __ffsll(m1) - 1);                \
        outb[RROW] = (float)cur;                                              \
        ldrow((RROW) - 6, PAu, PBu, VAu, VBu);                                \
    }

    // groups of 6: r = 2046, 2040, ..., 6 -> rows 2046..1 (341 groups)
    for (int r = 2046; r >= 6; r -= 6) {
        BODY(pa0, pb0, va0, vb0, va1, vb1, r - 0)
        BODY(pa1, pb1, va1, vb1, va2, vb2, r - 1)
        BODY(pa2, pb2, va2, vb2, va3, vb3, r - 2)
        BODY(pa3, pb3, va3, vb3, va4, vb4, r - 3)
        BODY(pa4, pb4, va4, vb4, va5, vb5, r - 4)
        BODY(pa5, pb5, va5, vb5, va0, vb0, r - 5)   // slot0 reloaded above
    }
#undef BODY

    // peeled row 0 (t = 1): slot 0 holds row 0 (reloaded in last group);
    // vstar_{-1} = 0 -> alpha_0 = pot_0
    {
        const int cl = cur & 63;
        const float rl0 = __int_as_float(
            __builtin_amdgcn_readlane(__float_as_int(va0), cl));
        const float rl1 = __int_as_float(
            __builtin_amdgcn_readlane(__float_as_int(vb0), cl));
        const float smax = (cur & 64) ? rl1 : rl0;
        const int sw = cur ^ (l & 31);
        const float s0 = pa0 + Tl[l][sw];
        const float s1 = pb0 + Tl[l + 64][sw];
        const unsigned long long m0 = __ballot(s0 == smax);
        const unsigned long long m1 = __ballot(s1 == smax);
        cur = m0 ? (__ffsll(m0) - 1) : (64 + __ffsll(m1) - 1);
        outb[0] = (float)cur;
    }
}

// ===========================================================================
// FULL FALLBACK (bp4, 32 MiB workspace): verbatim verified kernels.
// ===========================================================================
__global__ __launch_bounds__(512)
__attribute__((amdgpu_waves_per_eu(2, 2)))
void viterbi_fwd(
    const float* __restrict__ pot,
    const float* __restrict__ trans,
    unsigned* __restrict__ bp4,
    int* __restrict__ lastTag)
{
    const int b   = blockIdx.x;
    const int tid = threadIdx.x;
    const int w   = tid >> 6;
    const int l   = tid & 63;
    const int d   = l & 3;
    const int j   = 16 * w + (l >> 2);
    const int fj  = FSKEW(j);
    const int ib  = 32 * d;

    __shared__ __align__(16) float alphabuf[2][160];

#define DECL_TR(K) float tr_##K = trans[(ib + (K)) * C_DIM + j];
    TR_LIST(DECL_TR)
#undef DECL_TR

    const float* potb = pot + (size_t)b * T_LEN * C_DIM;

    if (tid < C_DIM) alphabuf[1][FSKEW(tid)] = potb[tid];

    float pq0 = 0.f, pq1 = 0.f, pq2 = 0.f, pq3 = 0.f;
    if (d == 0) {
        pq0 = potb[1 * C_DIM + j];
        pq1 = potb[2 * C_DIM + j];
        pq2 = potb[3 * C_DIM + j];
        pq3 = potb[4 * C_DIM + j];
    }
    unsigned pack = 0;
    __syncthreads();

#define ADD_TR(K) s_[K] = a_[K] + tr_##K;

#define STEP(T_, C_, PQ_)                                                     \
    {                                                                         \
        const float* ac_ = &alphabuf[(T_) & 1][40 * d];                       \
        float a_[32];                                                         \
        _Pragma("unroll")                                                     \
        for (int e_ = 0; e_ < 8; ++e_)                                        \
            *(float4*)&a_[4 * e_] = *(const float4*)&ac_[4 * e_];             \
        float s_[32];                                                         \
        TR_LIST(ADD_TR)                                                       \
        float v16_[16]; int x16_[16];                                         \
        _Pragma("unroll")                                                     \
        for (int p_ = 0; p_ < 16; ++p_) {                                     \
            const bool g_ = s_[2 * p_ + 1] > s_[2 * p_];                      \
            v16_[p_] = g_ ? s_[2 * p_ + 1] : s_[2 * p_];                      \
            x16_[p_] = g_ ? 2 * p_ + 1 : 2 * p_;                              \
        }                                                                     \
        float v8_[8]; int x8_[8];                                             \
        _Pragma("unroll")                                                     \
        for (int p_ = 0; p_ < 8; ++p_) {                                      \
            const bool g_ = v16_[2 * p_ + 1] > v16_[2 * p_];                  \
            v8_[p_] = g_ ? v16_[2 * p_ + 1] : v16_[2 * p_];                   \
            x8_[p_] = g_ ? x16_[2 * p_ + 1] : x16_[2 * p_];                   \
        }                                                                     \
        float v4_[4]; int x4_[4];                                             \
        _Pragma("unroll")                                                     \
        for (int p_ = 0; p_ < 4; ++p_) {                                      \
            const bool g_ = v8_[2 * p_ + 1] > v8_[2 * p_];                    \
            v4_[p_] = g_ ? v8_[2 * p_ + 1] : v8_[2 * p_];                     \
            x4_[p_] = g_ ? x8_[2 * p_ + 1] : x8_[2 * p_];                     \
        }                                                                     \
        float v2_[2]; int x2_[2];                                             \
        _Pragma("unroll")                                                     \
        for (int p_ = 0; p_ < 2; ++p_) {                                      \
            const bool g_ = v4_[2 * p_ + 1] > v4_[2 * p_];                    \
            v2_[p_] = g_ ? v4_[2 * p_ + 1] : v4_[2 * p_];                     \
            x2_[p_] = g_ ? x4_[2 * p_ + 1] : x4_[2 * p_];                     \
        }                                                                     \
        const bool gf_ = v2_[1] > v2_[0];                                     \
        float v_ = gf_ ? v2_[1] : v2_[0];                                     \
        int   x_ = ib + (gf_ ? x2_[1] : x2_[0]);                              \
        {                                                                     \
            const float pv_ = __int_as_float(__builtin_amdgcn_update_dpp(     \
                0, __float_as_int(v_), 0xB1, 0xF, 0xF, true));                \
            const int   px_ = __builtin_amdgcn_update_dpp(                    \
                0, x_, 0xB1, 0xF, 0xF, true);                                 \
            const bool  pl_ = d & 1;                                          \
            const bool  tk_ = (pv_ > v_) || (pl_ && (pv_ == v_));             \
            if (tk_) { v_ = pv_; x_ = px_; }                                  \
        }                                                                     \
        {                                                                     \
            const float pv_ = __int_as_float(__builtin_amdgcn_update_dpp(     \
                0, __float_as_int(v_), 0x4E, 0xF, 0xF, true));                \
            const int   px_ = __builtin_amdgcn_update_dpp(                    \
                0, x_, 0x4E, 0xF, 0xF, true);                                 \
            const bool  pl_ = (d >> 1) & 1;                                   \
            const bool  tk_ = (pv_ > v_) || (pl_ && (pv_ == v_));             \
            if (tk_) { v_ = pv_; x_ = px_; }                                  \
        }                                                                     \
        if (d == 0) {                                                         \
            alphabuf[((T_) + 1) & 1][fj] = v_ + (PQ_);                        \
            pack |= (unsigned)x_ << (8 * (C_));                               \
            if ((C_) == 3) {                                                  \
                bp4[((size_t)(((T_) - 1) >> 2) * B_DIM + b) * C_DIM + j] =    \
                    pack;                                                     \
                pack = 0;                                                     \
            }                                                                 \
            if ((T_) + 4 < T_LEN) PQ_ = potb[((T_) + 4) * C_DIM + j];         \
        }                                                                     \
        LDS_BARRIER();                                                        \
    }

    for (int t = 1; t < 2045; t += 4) {
        STEP(t + 0, 0, pq0)
        STEP(t + 1, 1, pq1)
        STEP(t + 2, 2, pq2)
        STEP(t + 3, 3, pq3)
    }
    STEP(2045, 0, pq0)
    STEP(2046, 1, pq1)
    STEP(2047, 2, pq2)
    if (d == 0)
        bp4[((size_t)511 * B_DIM + b) * C_DIM + j] = pack;
#undef STEP
#undef ADD_TR

    if (tid < 64) {
        const float* af = alphabuf[0];
        const float v0 = af[FSKEW(tid)];
        const float v1 = af[FSKEW(tid + 64)];
        float v = v0; int x = tid;
        if (v1 > v0) { v = v1; x = tid + 64; }
#pragma unroll
        for (int mk = 1; mk < 64; mk <<= 1) {
            const float pv = __shfl_xor(v, mk);
            const int   px = __shfl_xor(x, mk);
            if (pv > v || (pv == v && px < x)) { v = pv; x = px; }
        }
        if (tid == 0) lastTag[b] = x;
    }
}

__global__ __launch_bounds__(64, 1) void viterbi_bwd(
    const unsigned* __restrict__ bp4,
    const int* __restrict__ lastTag,
    float* __restrict__ out)
{
    const int b = blockIdx.x;
    const int l = threadIdx.x;
    float* outb = out + (size_t)b * T_LEN;

    unsigned qa0 = 0, qb0 = 0, qa1 = 0, qb1 = 0,
             qa2 = 0, qb2 = 0, qa3 = 0, qb3 = 0;

    auto ld = [&](int s4, unsigned& A, unsigned& B) {
        if (s4 >= 0) {
            const unsigned* r = bp4 + ((size_t)s4 * B_DIM + b) * C_DIM;
            A = r[l];
            B = r[l + 64];
        }
    };
    ld(511, qa0, qb0);
    ld(510, qa1, qb1);
    ld(509, qa2, qb2);
    ld(508, qa3, qb3);

    int cur = lastTag[b];

    auto ext = [&](unsigned rA, unsigned rB, int c, int byte) -> int {
        const int addr = (c & 63) << 2;
        const int vA = __builtin_amdgcn_ds_bpermute(addr, (int)rA);
        const int vB = __builtin_amdgcn_ds_bpermute(addr, (int)rB);
        const int v = (c & 64) ? vB : vA;
        return (v >> (byte * 8)) & 0xFF;
    };

    {
        const unsigned rA = qa0, rB = qb0;
        const float t3 = (float)cur;
        cur = ext(rA, rB, cur, 2); const float t2 = (float)cur;
        cur = ext(rA, rB, cur, 1); const float t1 = (float)cur;
        cur = ext(rA, rB, cur, 0); const float t0 = (float)cur;
        if (l == 0) *(float4*)(outb + 4 * 511) = make_float4(t0, t1, t2, t3);
        qa0 = qa1; qb0 = qb1; qa1 = qa2; qb1 = qb2; qa2 = qa3; qb2 = qb3;
        ld(507, qa3, qb3);
    }

    for (int s4 = 510; s4 >= 0; --s4) {
        const unsigned rA = qa0, rB = qb0;
        cur = ext(rA, rB, cur, 3); const float t3 = (float)cur;
        cur = ext(rA, rB, cur, 2); const float t2 = (float)cur;
        cur = ext(rA, rB, cur, 1); const float t1 = (float)cur;
        cur = ext(rA, rB, cur, 0); const float t0 = (float)cur;
        if (l == 0) *(float4*)(outb + 4 * s4) = make_float4(t0, t1, t2, t3);
        qa0 = qa1; qb0 = qb1; qa1 = qa2; qb1 = qb2; qa2 = qa3; qb2 = qb3;
        ld(s4 - 4, qa3, qb3);
    }
}

extern "C" void kernel_launch(void* const* d_in, const int* in_sizes, int n_in,
                              void* d_out, int out_size, void* d_ws, size_t ws_size,
                              hipStream_t stream)
{
    const float* pot   = (const float*)d_in[0];   // [128, 2048, 128] f32
    const float* trans = (const float*)d_in[1];   // [128, 128] f32
    float* out = (float*)d_out;                   // [128, 2048] f32 (tags)

    const size_t vstarBytes = (size_t)B_DIM * NSTEP * C_DIM * sizeof(float); // 134,152,192

    if (ws_size >= vstarBytes + 512) {
        // V*-store forward + reduction-free backtrack (static 6-slot queue)
        float* vstarG = (float*)d_ws;
        int* lastTag  = (int*)((char*)d_ws + vstarBytes);
        viterbi_fwd_a<<<B_DIM, 512, 0, stream>>>(pot, trans, vstarG, lastTag);
        viterbi_bwd_v<<<B_DIM, 64, 0, stream>>>(pot, vstarG, trans, lastTag, out);
    } else {
        // FALLBACK: bp4 path (32 MiB workspace)
        unsigned* bp4 = (unsigned*)d_ws;
        int* lastTag  = (int*)((char*)d_ws + (size_t)NS4 * B_DIM * C_DIM * 4);
        viterbi_fwd<<<B_DIM, 512, 0, stream>>>(pot, trans, bp4, lastTag);
        viterbi_bwd<<<B_DIM, 64, 0, stream>>>(bp4, lastTag, out);
    }
}

// Round 8
// 905.941 us; speedup vs baseline: 1.2190x; 1.0667x over previous
//
#include <hip/hip_runtime.h>
#include <cstdint>
#include <cstddef>

#define B_DIM 128
#define T_LEN 2048
#define C_DIM 128
#define NSTEP (T_LEN - 1)   // 2047 transition steps
#define NS4   512           // bp4-path dword-rows

// Skew for 32-float chunks: F(x) = x + 8*(x>>5) (chunk c at 40c). Verified
// conflict-free (R1/R5/R7: SQ_LDS_BANK_CONFLICT == 0).
#define FSKEW(x) ((x) + 8 * ((x) >> 5))

// Barrier WITHOUT vmcnt drain: cross-wave LDS visibility only needs
// lgkmcnt(0). Global loads/stores stay in flight across the barrier.
#define LDS_BARRIER() asm volatile("s_waitcnt lgkmcnt(0)\n\ts_barrier" ::: "memory")

#define TR_LIST(X) \
    X(0)  X(1)  X(2)  X(3)  X(4)  X(5)  X(6)  X(7)  \
    X(8)  X(9)  X(10) X(11) X(12) X(13) X(14) X(15) \
    X(16) X(17) X(18) X(19) X(20) X(21) X(22) X(23) \
    X(24) X(25) X(26) X(27) X(28) X(29) X(30) X(31)

template <int CTRL>
__device__ __forceinline__ float dppf(float x)
{
    return __int_as_float(__builtin_amdgcn_update_dpp(
        0, __float_as_int(x), CTRL, 0xF, 0xF, true));
}

// exact 32-way max, fuses to v_max3 chains (static indexing only)
__device__ __forceinline__ float max32(const float s[32])
{
    float u[11];
#pragma unroll
    for (int p = 0; p < 10; ++p)
        u[p] = fmaxf(fmaxf(s[3 * p], s[3 * p + 1]), s[3 * p + 2]);
    u[10] = fmaxf(s[30], s[31]);
    const float w0 = fmaxf(fmaxf(u[0], u[1]), u[2]);
    const float w1 = fmaxf(fmaxf(u[3], u[4]), u[5]);
    const float w2 = fmaxf(fmaxf(u[6], u[7]), u[8]);
    const float w3 = fmaxf(u[9], u[10]);
    return fmaxf(fmaxf(w0, w1), fmaxf(w2, w3));
}

// ===========================================================================
// Forward, value-only, FULLY BRANCHLESS (R5/R7-verified: ~595 us, 0
// bank conflicts). One block per batch, 512 threads = 8 waves (2/SIMD).
// Wave w owns j in [16w,16w+16); lane l: j = 16w + (l>>2), d = l&3,
// i in [32d,32d+32). All-lane dup writes (post-DPP all 4 quad lanes hold
// v_), clamped unconditional prefetch => precise vmcnt counting.
// ===========================================================================
__global__ __launch_bounds__(512)
__attribute__((amdgpu_waves_per_eu(2, 2)))
void viterbi_fwd_a(
    const float* __restrict__ pot,
    const float* __restrict__ trans,
    float* __restrict__ vstarG,        // [B][2047][C]: row t-1 = vstar_t
    int* __restrict__ lastTag)
{
    const int b   = blockIdx.x;
    const int tid = threadIdx.x;
    const int w   = tid >> 6;
    const int l   = tid & 63;
    const int d   = l & 3;             // i-chunk: [32d, 32d+32)
    const int j   = 16 * w + (l >> 2);
    const int fj  = FSKEW(j);
    const int ib  = 32 * d;

    __shared__ __align__(16) float alphabuf[2][160];

#define DECL_TR(K) const float tr_##K = trans[(ib + (K)) * C_DIM + j];
    TR_LIST(DECL_TR)
#undef DECL_TR

    const float* potb = pot + (size_t)b * T_LEN * C_DIM;
    float* vG = vstarG + (size_t)b * NSTEP * C_DIM;

    // alpha0 = pot[:,0] into buf[1] (step t=1 reads buf[t&1]=buf[1])
    if (tid < C_DIM) alphabuf[1][FSKEW(tid)] = potb[tid];

    // pot prefetch queue, depth 4, ALL lanes (branchless)
    float pq0 = potb[1 * C_DIM + j];
    float pq1 = potb[2 * C_DIM + j];
    float pq2 = potb[3 * C_DIM + j];
    float pq3 = potb[4 * C_DIM + j];
    __syncthreads();   // init barrier: full drain once, fine

#define ADD_TR(K) s_[K] = a_[K] + tr_##K;

#define STEP_A(T_, PQ_)                                                       \
    {                                                                         \
        const float* ac_ = &alphabuf[(T_) & 1][40 * d];                       \
        float a_[32];                                                         \
        _Pragma("unroll")                                                     \
        for (int e_ = 0; e_ < 8; ++e_)                                        \
            *(float4*)&a_[4 * e_] = *(const float4*)&ac_[4 * e_];             \
        float s_[32];                                                         \
        TR_LIST(ADD_TR)                                                       \
        float v_ = max32(s_);                                                 \
        v_ = fmaxf(v_, dppf<0xB1>(v_));                                       \
        v_ = fmaxf(v_, dppf<0x4E>(v_));                                       \
        const float av_ = v_ + (PQ_);                                         \
        alphabuf[((T_) + 1) & 1][fj] = av_;                                   \
        vG[(size_t)((T_) - 1) * C_DIM + j] = v_;                              \
        const int tn_ = ((T_) + 4 < T_LEN) ? ((T_) + 4) : (T_LEN - 1);        \
        PQ_ = potb[tn_ * C_DIM + j];   /* clamped rows never consumed */      \
        LDS_BARRIER();                                                        \
    }

    // main loop: t = 1 .. 2044 (groups of 4 for the pot-queue rotation)
    for (int t = 1; t < 2045; t += 4) {
        STEP_A(t + 0, pq0)
        STEP_A(t + 1, pq1)
        STEP_A(t + 2, pq2)
        STEP_A(t + 3, pq3)
    }
    // tail: t = 2045, 2046, 2047
    STEP_A(2045, pq0)
    STEP_A(2046, pq1)
    STEP_A(2047, pq2)
#undef STEP_A
#undef ADD_TR

    // last_tag = first-index argmax of final alpha (in buf[0]), wave 0
    if (tid < 64) {
        const float* af = alphabuf[0];
        const float v0 = af[FSKEW(tid)];
        const float v1 = af[FSKEW(tid + 64)];
        float v = v0; int x = tid;
        if (v1 > v0) { v = v1; x = tid + 64; }
#pragma unroll
        for (int mk = 1; mk < 64; mk <<= 1) {
            const float pv = __shfl_xor(v, mk);
            const int   px = __shfl_xor(x, mk);
            if (pv > v || (pv == v && px < x)) { v = pv; x = px; }
        }
        if (tid == 0) lastTag[b] = x;
    }
}

// ===========================================================================
// Reduction-free backtrack, 31-SLOT static queue, 31 bodies per loop
// iteration (2046 = 31 * 66 exactly). R7 (6-slot) landed at 434 cyc/step
// for a ~145-cyc chain; residual attributed to a conservative waitcnt at
// the loop back-edge (~900-cyc drain per group = ~150/body at 6 bodies).
// At 31 bodies/iteration that amortizes to ~29/body, and the prefetch
// distance becomes 31 bodies (~9000 cyc >> 900-cyc HBM latency).
// Slot arrays are indexed ONLY with compile-time constants (fully
// unrolled) => stay in registers (+124 VGPR, fine at 1 wave/CU).
// Body: smax = vstar_{r+1}[cur] via readlane; alpha replay pa+va;
// T[:,cur] swizzled LDS gather; equality-ballot + ffs (first-index).
// ===========================================================================
__global__ __launch_bounds__(64, 1) void viterbi_bwd_v(
    const float* __restrict__ pot,
    const float* __restrict__ vstarG,
    const float* __restrict__ trans,
    const int* __restrict__ lastTag,
    float* __restrict__ out)
{
    const int b = blockIdx.x;
    const int l = threadIdx.x;
    float* outb = out + (size_t)b * T_LEN;
    const float* potb = pot + (size_t)b * T_LEN * C_DIM;
    const float* vbse = vstarG + (size_t)b * NSTEP * C_DIM;

    __shared__ float Tl[C_DIM][C_DIM];   // 64 KiB, swizzled
    for (int k = l; k < C_DIM * C_DIM; k += 64) {
        const int i = k >> 7;
        const int jj = k & 127;
        Tl[i][jj ^ (i & 31)] = trans[k];
    }

    // 31 static slots; slot u holds rows descending by 31.
    float pa[31], pb[31], va[31], vb[31];
    auto ldrow = [&](int r, float& PA, float& PB, float& VA, float& VB) {
        const int rr = (r > 0) ? r : 0;        // clamped, branchless
        PA = potb[(size_t)rr * C_DIM + l];
        PB = potb[(size_t)rr * C_DIM + l + 64];
        VA = vbse[(size_t)rr * C_DIM + l];
        VB = vbse[(size_t)rr * C_DIM + l + 64];
    };
#pragma unroll
    for (int u = 0; u < 31; ++u)
        ldrow(2046 - u, pa[u], pb[u], va[u], vb[u]);

    int cur = lastTag[b];
    outb[T_LEN - 1] = (float)cur;        // uniform all-lane store
    __syncthreads();   // Tl visibility

    // group loop: rbase = 2046, 2015, ..., 31 (66 iterations)
    // body u processes row R = rbase - u; consumes slot u (row R) for the
    // smax readlane and slot (u+1)%31 (row R-1) for the alpha replay;
    // reloads slot u with row R-31 (consumed 31 bodies later).
    for (int rbase = 2046; rbase >= 31; rbase -= 31) {
#pragma unroll
        for (int u = 0; u < 31; ++u) {
            const int R = rbase - u;
            const int un = (u + 1) % 31;       // compile-time after unroll
            const int cl = cur & 63;
            const float rl0 = __int_as_float(
                __builtin_amdgcn_readlane(__float_as_int(va[u]), cl));
            const float rl1 = __int_as_float(
                __builtin_amdgcn_readlane(__float_as_int(vb[u]), cl));
            const float smax = (cur & 64) ? rl1 : rl0;
            const int sw = cur ^ (l & 31);
            const float c0 = Tl[l][sw];
            const float c1 = Tl[l + 64][sw];
            const float s0 = (pa[u] + va[un]) + c0;
            const float s1 = (pb[u] + vb[un]) + c1;
            const unsigned long long m0 = __ballot(s0 == smax);
            const unsigned long long m1 = __ballot(s1 == smax);
            cur = m0 ? (__ffsll(m0) - 1) : (64 + __ffsll(m1) - 1);
            outb[R] = (float)cur;              // uniform all-lane store
            ldrow(R - 31, pa[u], pb[u], va[u], vb[u]);
        }
    }

    // peeled row 0 (t = 1): after the last group (rows 31..1), slot 0 was
    // reloaded with row 0 (clamped). vstar_{-1} = 0 -> alpha_0 = pot_0.
    {
        const int cl = cur & 63;
        const float rl0 = __int_as_float(
            __builtin_amdgcn_readlane(__float_as_int(va[0]), cl));
        const float rl1 = __int_as_float(
            __builtin_amdgcn_readlane(__float_as_int(vb[0]), cl));
        const float smax = (cur & 64) ? rl1 : rl0;
        const int sw = cur ^ (l & 31);
        const float s0 = pa[0] + Tl[l][sw];
        const float s1 = pb[0] + Tl[l + 64][sw];
        const unsigned long long m0 = __ballot(s0 == smax);
        const unsigned long long m1 = __ballot(s1 == smax);
        cur = m0 ? (__ffsll(m0) - 1) : (64 + __ffsll(m1) - 1);
        outb[0] = (float)cur;
    }
}

// ===========================================================================
// FULL FALLBACK (bp4, 32 MiB workspace): verbatim verified kernels.
// ===========================================================================
__global__ __launch_bounds__(512)
__attribute__((amdgpu_waves_per_eu(2, 2)))
void viterbi_fwd(
    const float* __restrict__ pot,
    const float* __restrict__ trans,
    unsigned* __restrict__ bp4,
    int* __restrict__ lastTag)
{
    const int b   = blockIdx.x;
    const int tid = threadIdx.x;
    const int w   = tid >> 6;
    const int l   = tid & 63;
    const int d   = l & 3;
    const int j   = 16 * w + (l >> 2);
    const int fj  = FSKEW(j);
    const int ib  = 32 * d;

    __shared__ __align__(16) float alphabuf[2][160];

#define DECL_TR(K) float tr_##K = trans[(ib + (K)) * C_DIM + j];
    TR_LIST(DECL_TR)
#undef DECL_TR

    const float* potb = pot + (size_t)b * T_LEN * C_DIM;

    if (tid < C_DIM) alphabuf[1][FSKEW(tid)] = potb[tid];

    float pq0 = 0.f, pq1 = 0.f, pq2 = 0.f, pq3 = 0.f;
    if (d == 0) {
        pq0 = potb[1 * C_DIM + j];
        pq1 = potb[2 * C_DIM + j];
        pq2 = potb[3 * C_DIM + j];
        pq3 = potb[4 * C_DIM + j];
    }
    unsigned pack = 0;
    __syncthreads();

#define ADD_TR(K) s_[K] = a_[K] + tr_##K;

#define STEP(T_, C_, PQ_)                                                     \
    {                                                                         \
        const float* ac_ = &alphabuf[(T_) & 1][40 * d];                       \
        float a_[32];                                                         \
        _Pragma("unroll")                                                     \
        for (int e_ = 0; e_ < 8; ++e_)                                        \
            *(float4*)&a_[4 * e_] = *(const float4*)&ac_[4 * e_];             \
        float s_[32];                                                         \
        TR_LIST(ADD_TR)                                                       \
        float v16_[16]; int x16_[16];                                         \
        _Pragma("unroll")                                                     \
        for (int p_ = 0; p_ < 16; ++p_) {                                     \
            const bool g_ = s_[2 * p_ + 1] > s_[2 * p_];                      \
            v16_[p_] = g_ ? s_[2 * p_ + 1] : s_[2 * p_];                      \
            x16_[p_] = g_ ? 2 * p_ + 1 : 2 * p_;                              \
        }                                                                     \
        float v8_[8]; int x8_[8];                                             \
        _Pragma("unroll")                                                     \
        for (int p_ = 0; p_ < 8; ++p_) {                                      \
            const bool g_ = v16_[2 * p_ + 1] > v16_[2 * p_];                  \
            v8_[p_] = g_ ? v16_[2 * p_ + 1] : v16_[2 * p_];                   \
            x8_[p_] = g_ ? x16_[2 * p_ + 1] : x16_[2 * p_];                   \
        }                                                                     \
        float v4_[4]; int x4_[4];                                             \
        _Pragma("unroll")                                                     \
        for (int p_ = 0; p_ < 4; ++p_) {                                      \
            const bool g_ = v8_[2 * p_ + 1] > v8_[2 * p_];                    \
            v4_[p_] = g_ ? v8_[2 * p_ + 1] : v8_[2 * p_];                     \
            x4_[p_] = g_ ? x8_[2 * p_ + 1] : x8_[2 * p_];                     \
        }                                                                     \
        float v2_[2]; int x2_[2];                                             \
        _Pragma("unroll")                                                     \
        for (int p_ = 0; p_ < 2; ++p_) {                                      \
            const bool g_ = v4_[2 * p_ + 1] > v4_[2 * p_];                    \
            v2_[p_] = g_ ? v4_[2 * p_ + 1] : v4_[2 * p_];                     \
            x2_[p_] = g_ ? x4_[2 * p_ + 1] : x4_[2 * p_];                     \
        }                                                                     \
        const bool gf_ = v2_[1] > v2_[0];                                     \
        float v_ = gf_ ? v2_[1] : v2_[0];                                     \
        int   x_ = ib + (gf_ ? x2_[1] : x2_[0]);                              \
        {                                                                     \
            const float pv_ = __int_as_float(__builtin_amdgcn_update_dpp(     \
                0, __float_as_int(v_), 0xB1, 0xF, 0xF, true));                \
            const int   px_ = __builtin_amdgcn_update_dpp(                    \
                0, x_, 0xB1, 0xF, 0xF, true);                                 \
            const bool  pl_ = d & 1;                                          \
            const bool  tk_ = (pv_ > v_) || (pl_ && (pv_ == v_));             \
            if (tk_) { v_ = pv_; x_ = px_; }                                  \
        }                                                                     \
        {                                                                     \
            const float pv_ = __int_as_float(__builtin_amdgcn_update_dpp(     \
                0, __float_as_int(v_), 0x4E, 0xF, 0xF, true));                \
            const int   px_ = __builtin_amdgcn_update_dpp(                    \
                0, x_, 0x4E, 0xF, 0xF, true);                                 \
            const bool  pl_ = (d >> 1) & 1;                                   \
            const bool  tk_ = (pv_ > v_) || (pl_ && (pv_ == v_));             \
            if (tk_) { v_ = pv_; x_ = px_; }                                  \
        }                                                                     \
        if (d == 0) {                                                         \
            alphabuf[((T_) + 1) & 1][fj] = v_ + (PQ_);                        \
            pack |= (unsigned)x_ << (8 * (C_));                               \
            if ((C_) == 3) {                                                  \
                bp4[((size_t)(((T_) - 1) >> 2) * B_DIM + b) * C_DIM + j] =    \
                    pack;                                                     \
                pack = 0;                                                     \
            }                                                                 \
            if ((T_) + 4 < T_LEN) PQ_ = potb[((T_) + 4) * C_DIM + j];         \
        }                                                                     \
        LDS_BARRIER();                                                        \
    }

    for (int t = 1; t < 2045; t += 4) {
        STEP(t + 0, 0, pq0)
        STEP(t + 1, 1, pq1)
        STEP(t + 2, 2, pq2)
        STEP(t + 3, 3, pq3)
    }
    STEP(2045, 0, pq0)
    STEP(2046, 1, pq1)
    STEP(2047, 2, pq2)
    if (d == 0)
        bp4[((size_t)511 * B_DIM + b) * C_DIM + j] = pack;
#undef STEP
#undef ADD_TR

    if (tid < 64) {
        const float* af = alphabuf[0];
        const float v0 = af[FSKEW(tid)];
        const float v1 = af[FSKEW(tid + 64)];
        float v = v0; int x = tid;
        if (v1 > v0) { v = v1; x = tid + 64; }
#pragma unroll
        for (int mk = 1; mk < 64; mk <<= 1) {
            const float pv = __shfl_xor(v, mk);
            const int   px = __shfl_xor(x, mk);
            if (pv > v || (pv == v && px < x)) { v = pv; x = px; }
        }
        if (tid == 0) lastTag[b] = x;
    }
}

__global__ __launch_bounds__(64, 1) void viterbi_bwd(
    const unsigned* __restrict__ bp4,
    const int* __restrict__ lastTag,
    float* __restrict__ out)
{
    const int b = blockIdx.x;
    const int l = threadIdx.x;
    float* outb = out + (size_t)b * T_LEN;

    unsigned qa0 = 0, qb0 = 0, qa1 = 0, qb1 = 0,
             qa2 = 0, qb2 = 0, qa3 = 0, qb3 = 0;

    auto ld = [&](int s4, unsigned& A, unsigned& B) {
        if (s4 >= 0) {
            const unsigned* r = bp4 + ((size_t)s4 * B_DIM + b) * C_DIM;
            A = r[l];
            B = r[l + 64];
        }
    };
    ld(511, qa0, qb0);
    ld(510, qa1, qb1);
    ld(509, qa2, qb2);
    ld(508, qa3, qb3);

    int cur = lastTag[b];

    auto ext = [&](unsigned rA, unsigned rB, int c, int byte) -> int {
        const int addr = (c & 63) << 2;
        const int vA = __builtin_amdgcn_ds_bpermute(addr, (int)rA);
        const int vB = __builtin_amdgcn_ds_bpermute(addr, (int)rB);
        const int v = (c & 64) ? vB : vA;
        return (v >> (byte * 8)) & 0xFF;
    };

    {
        const unsigned rA = qa0, rB = qb0;
        const float t3 = (float)cur;
        cur = ext(rA, rB, cur, 2); const float t2 = (float)cur;
        cur = ext(rA, rB, cur, 1); const float t1 = (float)cur;
        cur = ext(rA, rB, cur, 0); const float t0 = (float)cur;
        if (l == 0) *(float4*)(outb + 4 * 511) = make_float4(t0, t1, t2, t3);
        qa0 = qa1; qb0 = qb1; qa1 = qa2; qb1 = qb2; qa2 = qa3; qb2 = qb3;
        ld(507, qa3, qb3);
    }

    for (int s4 = 510; s4 >= 0; --s4) {
        const unsigned rA = qa0, rB = qb0;
        cur = ext(rA, rB, cur, 3); const float t3 = (float)cur;
        cur = ext(rA, rB, cur, 2); const float t2 = (float)cur;
        cur = ext(rA, rB, cur, 1); const float t1 = (float)cur;
        cur = ext(rA, rB, cur, 0); const float t0 = (float)cur;
        if (l == 0) *(float4*)(outb + 4 * s4) = make_float4(t0, t1, t2, t3);
        qa0 = qa1; qb0 = qb1; qa1 = qa2; qb1 = qb2; qa2 = qa3; qb2 = qb3;
        ld(s4 - 4, qa3, qb3);
    }
}

extern "C" void kernel_launch(void* const* d_in, const int* in_sizes, int n_in,
                              void* d_out, int out_size, void* d_ws, size_t ws_size,
                              hipStream_t stream)
{
    const float* pot   = (const float*)d_in[0];   // [128, 2048, 128] f32
    const float* trans = (const float*)d_in[1];   // [128, 128] f32
    float* out = (float*)d_out;                   // [128, 2048] f32 (tags)

    const size_t vstarBytes = (size_t)B_DIM * NSTEP * C_DIM * sizeof(float); // 134,152,192

    if (ws_size >= vstarBytes + 512) {
        // V*-store forward + reduction-free backtrack (31-slot queue)
        float* vstarG = (float*)d_ws;
        int* lastTag  = (int*)((char*)d_ws + vstarBytes);
        viterbi_fwd_a<<<B_DIM, 512, 0, stream>>>(pot, trans, vstarG, lastTag);
        viterbi_bwd_v<<<B_DIM, 64, 0, stream>>>(pot, vstarG, trans, lastTag, out);
    } else {
        // FALLBACK: bp4 path (32 MiB workspace)
        unsigned* bp4 = (unsigned*)d_ws;
        int* lastTag  = (int*)((char*)d_ws + (size_t)NS4 * B_DIM * C_DIM * 4);
        viterbi_fwd<<<B_DIM, 512, 0, stream>>>(pot, trans, bp4, lastTag);
        viterbi_bwd<<<B_DIM, 64, 0, stream>>>(bp4, lastTag, out);
    }
}